// Round 2
// baseline (183.893 us; speedup 1.0000x reference)
//
#include <hip/hip_runtime.h>

// ActivationDelta: out = where(ACT_MASK[col] & (v != 0), clamp(v + delta, 0, 1), v)
// ACT columns (FEAT_DIM=2133): {0, 81, 165+3j : j in [0,40)}  (42 columns)
// Memory-bound streaming op: 426.6 MB in + 426.6 MB out. Strategy: float4
// lanes, 4x unrolled independent loads for MLP, nontemporal hints (no reuse).

#define FEAT_DIM 2133u

typedef float f32x4 __attribute__((ext_vector_type(4)));

__device__ __forceinline__ bool is_act_col(unsigned c) {
    // unsigned wrap: c < 165 -> (c-165) is huge -> range check fails
    unsigned d = c - 165u;
    return (c == 0u) | (c == 81u) | ((d <= 117u) & (d % 3u == 0u));
}

__device__ __forceinline__ f32x4 proc4(f32x4 v, unsigned c0, float dlt) {
    f32x4 r;
#pragma unroll
    for (int k = 0; k < 4; ++k) {
        unsigned c = c0 + (unsigned)k;
        c = (c >= FEAT_DIM) ? (c - FEAT_DIM) : c;
        float x = v[k];
        float b = fminf(fmaxf(x + dlt, 0.0f), 1.0f);
        bool ap = is_act_col(c) & (x != 0.0f);
        r[k] = ap ? b : x;
    }
    return r;
}

__global__ void __launch_bounds__(256, 8)
ActivationDelta_19318762897441_kernel(const float* __restrict__ in,
                                      const float* __restrict__ dptr,
                                      float* __restrict__ out,
                                      unsigned n4, unsigned n)
{
    const float dlt = dptr[0];
    const unsigned stride = gridDim.x * blockDim.x;
    const unsigned tid = blockIdx.x * blockDim.x + threadIdx.x;

    const f32x4* __restrict__ in4 = reinterpret_cast<const f32x4*>(in);
    f32x4* __restrict__ out4      = reinterpret_cast<f32x4*>(out);

    unsigned i = tid;
    // main loop: 4 independent float4 loads in flight per wave
    for (; i + 3u * stride < n4; i += 4u * stride) {
        f32x4 v0 = __builtin_nontemporal_load(&in4[i]);
        f32x4 v1 = __builtin_nontemporal_load(&in4[i + stride]);
        f32x4 v2 = __builtin_nontemporal_load(&in4[i + 2u * stride]);
        f32x4 v3 = __builtin_nontemporal_load(&in4[i + 3u * stride]);

        v0 = proc4(v0, (i * 4u) % FEAT_DIM, dlt);
        v1 = proc4(v1, ((i + stride) * 4u) % FEAT_DIM, dlt);
        v2 = proc4(v2, ((i + 2u * stride) * 4u) % FEAT_DIM, dlt);
        v3 = proc4(v3, ((i + 3u * stride) * 4u) % FEAT_DIM, dlt);

        __builtin_nontemporal_store(v0, &out4[i]);
        __builtin_nontemporal_store(v1, &out4[i + stride]);
        __builtin_nontemporal_store(v2, &out4[i + 2u * stride]);
        __builtin_nontemporal_store(v3, &out4[i + 3u * stride]);
    }
    // remainder float4s
    for (; i < n4; i += stride) {
        f32x4 v = __builtin_nontemporal_load(&in4[i]);
        v = proc4(v, (i * 4u) % FEAT_DIM, dlt);
        __builtin_nontemporal_store(v, &out4[i]);
    }
    // scalar tail (n % 4; n = 50000*2133 is divisible by 4, but be safe)
    for (unsigned j = n4 * 4u + tid; j < n; j += stride) {
        unsigned c = j % FEAT_DIM;
        float x = in[j];
        float b = fminf(fmaxf(x + dlt, 0.0f), 1.0f);
        bool ap = is_act_col(c) & (x != 0.0f);
        out[j] = ap ? b : x;
    }
}

extern "C" void kernel_launch(void* const* d_in, const int* in_sizes, int n_in,
                              void* d_out, int out_size, void* d_ws, size_t ws_size,
                              hipStream_t stream) {
    const float* in  = (const float*)d_in[0];
    const float* dlt = (const float*)d_in[1];
    float* out       = (float*)d_out;

    const unsigned n  = (unsigned)in_sizes[0];
    const unsigned n4 = n / 4u;

    const int block = 256;
    // 2048 blocks x 256 thr = 8 blocks/CU x 4 waves = 32 waves/CU (full TLP)
    unsigned want = (n4 + block - 1) / block;
    unsigned grid = want < 2048u ? (want ? want : 1u) : 2048u;

    ActivationDelta_19318762897441_kernel<<<dim3(grid), dim3(block), 0, stream>>>(
        in, dlt, out, n4, n);
}

// Round 3
// 164.665 us; speedup vs baseline: 1.1168x; 1.1168x over previous
//
#include <hip/hip_runtime.h>

// ActivationDelta: out = where(ACT_MASK[col] & (v != 0), clamp(v + delta, 0, 1), v)
// ACT columns (FEAT_DIM=2133): {0, 81, 165+3j : j in [0,40)}  (42 columns)
// Memory-bound streaming: 426.6 MB in + 426.6 MB out.
// R3: block-contiguous x4 unroll (4 coalesced loads in flight, 16KB/block-tile),
//     normal (cached) loads/stores — R2 showed nt + 8MB-strided unroll regresses.

#define FEAT_DIM 2133u

typedef float f32x4 __attribute__((ext_vector_type(4)));

__device__ __forceinline__ bool is_act_col(unsigned c) {
    // unsigned wrap: c < 165 -> (c-165) huge -> range check fails
    unsigned d = c - 165u;
    return (c == 0u) | (c == 81u) | ((d <= 117u) & (d % 3u == 0u));
}

__device__ __forceinline__ f32x4 proc4(f32x4 v, unsigned i /*float4 index*/, float dlt) {
    unsigned c0 = (i * 4u) % FEAT_DIM;
    f32x4 r;
#pragma unroll
    for (int k = 0; k < 4; ++k) {
        unsigned c = c0 + (unsigned)k;
        c = (c >= FEAT_DIM) ? (c - FEAT_DIM) : c;
        float x = v[k];
        float b = fminf(fmaxf(x + dlt, 0.0f), 1.0f);
        bool ap = is_act_col(c) & (x != 0.0f);
        r[k] = ap ? b : x;
    }
    return r;
}

__global__ void __launch_bounds__(256)
ActivationDelta_19318762897441_kernel(const float* __restrict__ in,
                                      const float* __restrict__ dptr,
                                      float* __restrict__ out,
                                      unsigned n4, unsigned ntiles, unsigned n)
{
    const float dlt = dptr[0];
    const unsigned t = threadIdx.x;

    const f32x4* __restrict__ in4 = reinterpret_cast<const f32x4*>(in);
    f32x4* __restrict__ out4      = reinterpret_cast<f32x4*>(out);

    // Main: each tile = 1024 consecutive float4s (16 KB), 4 per thread at +256.
    for (unsigned tile = blockIdx.x; tile < ntiles; tile += gridDim.x) {
        unsigned base = tile * 1024u + t;
        f32x4 v0 = in4[base];
        f32x4 v1 = in4[base + 256u];
        f32x4 v2 = in4[base + 512u];
        f32x4 v3 = in4[base + 768u];

        v0 = proc4(v0, base,         dlt);
        v1 = proc4(v1, base + 256u,  dlt);
        v2 = proc4(v2, base + 512u,  dlt);
        v3 = proc4(v3, base + 768u,  dlt);

        out4[base]         = v0;
        out4[base + 256u]  = v1;
        out4[base + 512u]  = v2;
        out4[base + 768u]  = v3;
    }

    // float4 tail after the last full tile
    for (unsigned i = ntiles * 1024u + blockIdx.x * 256u + t; i < n4;
         i += gridDim.x * 256u) {
        f32x4 v = in4[i];
        out4[i] = proc4(v, i, dlt);
    }

    // scalar tail (n % 4; n = 50000*2133 is divisible by 4, but be safe)
    for (unsigned j = n4 * 4u + blockIdx.x * 256u + t; j < n;
         j += gridDim.x * 256u) {
        unsigned c = j % FEAT_DIM;
        float x = in[j];
        float b = fminf(fmaxf(x + dlt, 0.0f), 1.0f);
        bool ap = is_act_col(c) & (x != 0.0f);
        out[j] = ap ? b : x;
    }
}

extern "C" void kernel_launch(void* const* d_in, const int* in_sizes, int n_in,
                              void* d_out, int out_size, void* d_ws, size_t ws_size,
                              hipStream_t stream) {
    const float* in  = (const float*)d_in[0];
    const float* dlt = (const float*)d_in[1];
    float* out       = (float*)d_out;

    const unsigned n      = (unsigned)in_sizes[0];
    const unsigned n4     = n / 4u;
    const unsigned ntiles = n4 / 1024u;

    const int block = 256;
    unsigned want = ntiles ? ntiles : 1u;
    unsigned grid = want < 2048u ? want : 2048u;

    ActivationDelta_19318762897441_kernel<<<dim3(grid), dim3(block), 0, stream>>>(
        in, dlt, out, n4, ntiles, n);
}

// Round 4
// 162.417 us; speedup vs baseline: 1.1322x; 1.0138x over previous
//
#include <hip/hip_runtime.h>

// ActivationDelta: out = where(ACT_MASK[col] & (v != 0), clamp(v + delta, 0, 1), v)
// ACT columns (FEAT_DIM=2133): {0, 81, 165+3j : j in [0,40)}  (42 columns)
// Memory-bound streaming: 426.6 MB in + 426.6 MB out.
// R4: identical to R3 except ONE change — nontemporal STORES (output is
//     write-once-never-read; avoid L2 write-allocate competing with the read
//     stream). Loads remain cached. R2's regression is attributed to the
//     8MB-strided unroll, not nt per se; this isolates nt-store.

#define FEAT_DIM 2133u

typedef float f32x4 __attribute__((ext_vector_type(4)));

__device__ __forceinline__ bool is_act_col(unsigned c) {
    // unsigned wrap: c < 165 -> (c-165) huge -> range check fails
    unsigned d = c - 165u;
    return (c == 0u) | (c == 81u) | ((d <= 117u) & (d % 3u == 0u));
}

__device__ __forceinline__ f32x4 proc4(f32x4 v, unsigned i /*float4 index*/, float dlt) {
    unsigned c0 = (i * 4u) % FEAT_DIM;
    f32x4 r;
#pragma unroll
    for (int k = 0; k < 4; ++k) {
        unsigned c = c0 + (unsigned)k;
        c = (c >= FEAT_DIM) ? (c - FEAT_DIM) : c;
        float x = v[k];
        float b = fminf(fmaxf(x + dlt, 0.0f), 1.0f);
        bool ap = is_act_col(c) & (x != 0.0f);
        r[k] = ap ? b : x;
    }
    return r;
}

__global__ void __launch_bounds__(256)
ActivationDelta_19318762897441_kernel(const float* __restrict__ in,
                                      const float* __restrict__ dptr,
                                      float* __restrict__ out,
                                      unsigned n4, unsigned ntiles, unsigned n)
{
    const float dlt = dptr[0];
    const unsigned t = threadIdx.x;

    const f32x4* __restrict__ in4 = reinterpret_cast<const f32x4*>(in);
    f32x4* __restrict__ out4      = reinterpret_cast<f32x4*>(out);

    // Main: each tile = 1024 consecutive float4s (16 KB), 4 per thread at +256.
    for (unsigned tile = blockIdx.x; tile < ntiles; tile += gridDim.x) {
        unsigned base = tile * 1024u + t;
        f32x4 v0 = in4[base];
        f32x4 v1 = in4[base + 256u];
        f32x4 v2 = in4[base + 512u];
        f32x4 v3 = in4[base + 768u];

        v0 = proc4(v0, base,         dlt);
        v1 = proc4(v1, base + 256u,  dlt);
        v2 = proc4(v2, base + 512u,  dlt);
        v3 = proc4(v3, base + 768u,  dlt);

        __builtin_nontemporal_store(v0, &out4[base]);
        __builtin_nontemporal_store(v1, &out4[base + 256u]);
        __builtin_nontemporal_store(v2, &out4[base + 512u]);
        __builtin_nontemporal_store(v3, &out4[base + 768u]);
    }

    // float4 tail after the last full tile
    for (unsigned i = ntiles * 1024u + blockIdx.x * 256u + t; i < n4;
         i += gridDim.x * 256u) {
        f32x4 v = in4[i];
        v = proc4(v, i, dlt);
        __builtin_nontemporal_store(v, &out4[i]);
    }

    // scalar tail (n % 4; n = 50000*2133 is divisible by 4, but be safe)
    for (unsigned j = n4 * 4u + blockIdx.x * 256u + t; j < n;
         j += gridDim.x * 256u) {
        unsigned c = j % FEAT_DIM;
        float x = in[j];
        float b = fminf(fmaxf(x + dlt, 0.0f), 1.0f);
        bool ap = is_act_col(c) & (x != 0.0f);
        out[j] = ap ? b : x;
    }
}

extern "C" void kernel_launch(void* const* d_in, const int* in_sizes, int n_in,
                              void* d_out, int out_size, void* d_ws, size_t ws_size,
                              hipStream_t stream) {
    const float* in  = (const float*)d_in[0];
    const float* dlt = (const float*)d_in[1];
    float* out       = (float*)d_out;

    const unsigned n      = (unsigned)in_sizes[0];
    const unsigned n4     = n / 4u;
    const unsigned ntiles = n4 / 1024u;

    const int block = 256;
    unsigned want = ntiles ? ntiles : 1u;
    unsigned grid = want < 2048u ? want : 2048u;

    ActivationDelta_19318762897441_kernel<<<dim3(grid), dim3(block), 0, stream>>>(
        in, dlt, out, n4, ntiles, n);
}